// Round 1
// baseline (1614.947 us; speedup 1.0000x reference)
//
#include <hip/hip_runtime.h>

// Problem constants (fixed by the reference)
#define NN 50000
#define NE 800000
#define ND 16
#define ED 16
#define H  128
#define OD 4
#define MT 32   // nodes per block in node GEMM

// ---------------------------------------------------------------------------
// h = x @ lift_w + lift_b        [NN, H]
// ---------------------------------------------------------------------------
__global__ __launch_bounds__(256) void lift_kernel(
    const float* __restrict__ x, const float* __restrict__ lw,
    const float* __restrict__ lb, float* __restrict__ h) {
  int idx = blockIdx.x * 256 + threadIdx.x;   // NN*H = 6.4M, exact multiple of 256
  int n = idx >> 7, k = idx & 127;
  float acc = lb[k];
  const float* xr = x + n * ND;
#pragma unroll
  for (int j = 0; j < ND; ++j) acc = fmaf(xr[j], lw[j * H + k], acc);
  h[idx] = acc;
}

// ---------------------------------------------------------------------------
// Fused node GEMM:
//   Hw  = h @ msg_w[i][0:128,:]                (message part from h[src])
//   agg = h @ root_w[i] + root_b[i]            (agg initialized with root path)
// 128 threads: thread t -> matrix (t>>6), columns 2*(t&63), 2*(t&63)+1
// 32-node tile staged in LDS.
// ---------------------------------------------------------------------------
__global__ __launch_bounds__(128) void node_gemm_kernel(
    const float* __restrict__ h, const float* __restrict__ wmsg,
    const float* __restrict__ wroot, const float* __restrict__ rb,
    float* __restrict__ Hw, float* __restrict__ agg) {
  __shared__ float4 hs[MT][H / 4];   // 16 KiB
  int n0 = blockIdx.x * MT;
  int t = threadIdx.x;

  // stage h tile (guard tail nodes)
  for (int i = t; i < MT * (H / 4); i += 128) {
    int n = i >> 5;        // H/4 == 32
    int c = i & 31;
    float4 v = make_float4(0.f, 0.f, 0.f, 0.f);
    if (n0 + n < NN) v = ((const float4*)(h + (size_t)(n0 + n) * H))[c];
    hs[n][c] = v;
  }
  __syncthreads();

  int mat = t >> 6;             // 0: msg weights, 1: root weights
  int c0 = (t & 63) * 2;        // two output columns
  const float* W = mat ? wroot : wmsg;

  float acc0[MT], acc1[MT];
  float b0 = mat ? rb[c0] : 0.f;
  float b1 = mat ? rb[c0 + 1] : 0.f;
#pragma unroll
  for (int n = 0; n < MT; ++n) { acc0[n] = b0; acc1[n] = b1; }

  for (int j = 0; j < H; j += 4) {
    float2 wa = *(const float2*)&W[(j + 0) * H + c0];
    float2 wb = *(const float2*)&W[(j + 1) * H + c0];
    float2 wc = *(const float2*)&W[(j + 2) * H + c0];
    float2 wd = *(const float2*)&W[(j + 3) * H + c0];
#pragma unroll
    for (int n = 0; n < MT; ++n) {
      float4 hv = hs[n][j >> 2];
      acc0[n] = fmaf(hv.x, wa.x, acc0[n]); acc1[n] = fmaf(hv.x, wa.y, acc1[n]);
      acc0[n] = fmaf(hv.y, wb.x, acc0[n]); acc1[n] = fmaf(hv.y, wb.y, acc1[n]);
      acc0[n] = fmaf(hv.z, wc.x, acc0[n]); acc1[n] = fmaf(hv.z, wc.y, acc1[n]);
      acc0[n] = fmaf(hv.w, wd.x, acc0[n]); acc1[n] = fmaf(hv.w, wd.y, acc1[n]);
    }
  }

  float* outp = mat ? agg : Hw;
#pragma unroll
  for (int n = 0; n < MT; ++n) {
    if (n0 + n < NN) {
      float2 v = make_float2(acc0[n], acc1[n]);
      *(float2*)&outp[(size_t)(n0 + n) * H + c0] = v;
    }
  }
}

// ---------------------------------------------------------------------------
// Per edge: msg = Hw[src] + (edge_attr @ W_e + msg_b); agg[dst] += msg (atomic)
// 128 threads per edge (one per hidden column), 2 edges per 256-thread block.
// ---------------------------------------------------------------------------
__global__ __launch_bounds__(256) void scatter_kernel(
    const int* __restrict__ ei, const float* __restrict__ ea,
    const float* __restrict__ we, const float* __restrict__ mb,
    const float* __restrict__ Hw, float* __restrict__ agg) {
  long long gid = (long long)blockIdx.x * 256 + threadIdx.x;
  int e = (int)(gid >> 7);
  int k = (int)(gid & 127);
  if (e >= NE) return;
  int s = ei[e];
  int d = ei[NE + e];
  const float* a = ea + (size_t)e * ED;
  float acc = mb[k] + Hw[(size_t)s * H + k];
#pragma unroll
  for (int j = 0; j < ED; ++j) acc = fmaf(a[j], we[j * H + k], acc);
  atomicAdd(&agg[(size_t)d * H + k], acc);
}

// ---------------------------------------------------------------------------
// h = act ? gelu(agg + h) : (agg + h)   (agg already holds root path + msgs)
// ---------------------------------------------------------------------------
__global__ __launch_bounds__(256) void update_kernel(
    const float* __restrict__ agg, float* __restrict__ h, int act) {
  int idx = blockIdx.x * 256 + threadIdx.x;   // NN*H exact multiple of 256
  float v = agg[idx] + h[idx];
  if (act) {
    float u = 0.7978845608028654f * (v + 0.044715f * v * v * v);
    v = 0.5f * v * (1.f + tanhf(u));
  }
  h[idx] = v;
}

// ---------------------------------------------------------------------------
// out = h @ proj_w + proj_b     [NN, OD]
// ---------------------------------------------------------------------------
__global__ __launch_bounds__(256) void proj_kernel(
    const float* __restrict__ h, const float* __restrict__ pw,
    const float* __restrict__ pb, float* __restrict__ out) {
  int idx = blockIdx.x * 256 + threadIdx.x;
  if (idx >= NN * OD) return;
  int n = idx >> 2, o = idx & 3;
  float acc = pb[o];
  const float* hr = h + (size_t)n * H;
#pragma unroll
  for (int j = 0; j < H; ++j) acc = fmaf(hr[j], pw[j * OD + o], acc);
  out[idx] = acc;
}

extern "C" void kernel_launch(void* const* d_in, const int* in_sizes, int n_in,
                              void* d_out, int out_size, void* d_ws, size_t ws_size,
                              hipStream_t stream) {
  const float* x       = (const float*)d_in[0];
  const int*   ei      = (const int*)d_in[1];     // [2, NE] int32
  const float* ea      = (const float*)d_in[2];
  const float* lift_w  = (const float*)d_in[3];
  const float* lift_b  = (const float*)d_in[4];
  const float* root_w  = (const float*)d_in[5];   // [3,128,128]
  const float* root_b  = (const float*)d_in[6];   // [3,128]
  const float* msg_w   = (const float*)d_in[7];   // [3,144,128]
  const float* msg_b   = (const float*)d_in[8];   // [3,128]
  const float* proj_w  = (const float*)d_in[9];
  const float* proj_b  = (const float*)d_in[10];
  float* out = (float*)d_out;

  float* h   = (float*)d_ws;                       // NN*H
  float* Hw  = h + (size_t)NN * H;                 // NN*H
  float* agg = Hw + (size_t)NN * H;                // NN*H
  // total ws use: 3 * 25.6 MB = 76.8 MB

  lift_kernel<<<(NN * H) / 256, 256, 0, stream>>>(x, lift_w, lift_b, h);

  for (int b = 0; b < 3; ++b) {
    const float* wmsg = msg_w + (size_t)b * (H + ED) * H;   // rows 0..127 -> h part
    const float* we   = wmsg + (size_t)H * H;               // rows 128..143 -> edge part
    const float* wrt  = root_w + (size_t)b * H * H;
    const float* rbb  = root_b + (size_t)b * H;
    const float* mbb  = msg_b + (size_t)b * H;

    node_gemm_kernel<<<(NN + MT - 1) / MT, 128, 0, stream>>>(h, wmsg, wrt, rbb, Hw, agg);
    scatter_kernel<<<(NE * 128) / 256, 256, 0, stream>>>(ei, ea, we, mbb, Hw, agg);
    update_kernel<<<(NN * H) / 256, 256, 0, stream>>>(agg, h, b < 2 ? 1 : 0);
  }

  proj_kernel<<<(NN * OD + 255) / 256, 256, 0, stream>>>(h, proj_w, proj_b, out);
}

// Round 2
// 646.536 us; speedup vs baseline: 2.4978x; 2.4978x over previous
//
#include <hip/hip_runtime.h>

// Problem constants (fixed by the reference)
#define NN 50000
#define NE 800000
#define ND 16
#define ED 16
#define H  128
#define OD 4
#define MT 32     // nodes per block in node GEMM
#define SCAN_T 512

// ---------------------------------------------------------------------------
// zero deg + cursor
// ---------------------------------------------------------------------------
__global__ __launch_bounds__(256) void zero_kernel(int* __restrict__ deg,
                                                   int* __restrict__ cursor) {
  int i = blockIdx.x * 256 + threadIdx.x;
  if (i < NN) { deg[i] = 0; cursor[i] = 0; }
}

// ---------------------------------------------------------------------------
// in-degree count
// ---------------------------------------------------------------------------
__global__ __launch_bounds__(256) void degcount_kernel(
    const int* __restrict__ ei, int* __restrict__ deg) {
  int e = blockIdx.x * 256 + threadIdx.x;
  if (e < NE) atomicAdd(&deg[ei[NE + e]], 1);
}

// ---------------------------------------------------------------------------
// prefix scan over deg -> offsets (exclusive). 3 kernels.
// ---------------------------------------------------------------------------
__global__ __launch_bounds__(SCAN_T) void scan_part_kernel(
    const int* __restrict__ deg, int* __restrict__ offsets,
    int* __restrict__ tops) {
  __shared__ int s[SCAN_T];
  int t = threadIdx.x;
  int i = blockIdx.x * SCAN_T + t;
  int v = (i < NN) ? deg[i] : 0;
  s[t] = v;
  __syncthreads();
  for (int off = 1; off < SCAN_T; off <<= 1) {
    int a = (t >= off) ? s[t - off] : 0;
    __syncthreads();
    s[t] += a;
    __syncthreads();
  }
  if (i < NN) offsets[i] = s[t] - v;     // exclusive within tile
  if (t == SCAN_T - 1) tops[blockIdx.x] = s[t];
}

__global__ void scan_tops_kernel(int* __restrict__ tops, int ntiles,
                                 int* __restrict__ offsets) {
  if (threadIdx.x == 0) {
    int run = 0;
    for (int b = 0; b < ntiles; ++b) { int v = tops[b]; tops[b] = run; run += v; }
    offsets[NN] = NE;
  }
}

__global__ __launch_bounds__(256) void scan_add_kernel(
    int* __restrict__ offsets, const int* __restrict__ tops) {
  int i = blockIdx.x * 256 + threadIdx.x;
  if (i < NN) offsets[i] += tops[i / SCAN_T];
}

// ---------------------------------------------------------------------------
// fill CSR: slot order within a node is nondeterministic but the SET is fixed
// ---------------------------------------------------------------------------
__global__ __launch_bounds__(256) void csr_fill_kernel(
    const int* __restrict__ ei, const int* __restrict__ offsets,
    int* __restrict__ cursor, int* __restrict__ csr_src,
    int* __restrict__ csr_eid) {
  int e = blockIdx.x * 256 + threadIdx.x;
  if (e >= NE) return;
  int d = ei[NE + e];
  int pos = atomicAdd(&cursor[d], 1);
  int slot = offsets[d] + pos;
  csr_src[slot] = ei[e];
  csr_eid[slot] = e;
}

// ---------------------------------------------------------------------------
// ea_agg[i] = sum over incoming edges of edge_attr[e]  (block-independent)
// 16 threads per node
// ---------------------------------------------------------------------------
__global__ __launch_bounds__(256) void ea_agg_kernel(
    const int* __restrict__ offsets, const int* __restrict__ csr_eid,
    const float* __restrict__ ea, float* __restrict__ ea_agg) {
  int t = threadIdx.x;
  int node = blockIdx.x * 16 + (t >> 4);
  if (node >= NN) return;
  int k = t & 15;
  int s = offsets[node], e = offsets[node + 1];
  float acc = 0.f;
  for (int p = s; p < e; ++p)
    acc += ea[(size_t)csr_eid[p] * ED + k];
  ea_agg[(size_t)node * ED + k] = acc;
}

// ---------------------------------------------------------------------------
// h = x @ lift_w + lift_b        [NN, H]
// ---------------------------------------------------------------------------
__global__ __launch_bounds__(256) void lift_kernel(
    const float* __restrict__ x, const float* __restrict__ lw,
    const float* __restrict__ lb, float* __restrict__ h) {
  int idx = blockIdx.x * 256 + threadIdx.x;
  int n = idx >> 7, k = idx & 127;
  float acc = lb[k];
  const float* xr = x + n * ND;
#pragma unroll
  for (int j = 0; j < ND; ++j) acc = fmaf(xr[j], lw[j * H + k], acc);
  h[idx] = acc;
}

// ---------------------------------------------------------------------------
// Fused node GEMM:
//   Hw   = h @ msg_w[i][0:128,:]
//   base = h @ root_w[i] + root_b[i] + h (identity) + ea_agg @ W_e + deg*mb
// wave 0 (t<64): msg matrix; wave 1 (t>=64): root matrix (+extras)
// ---------------------------------------------------------------------------
__global__ __launch_bounds__(128) void node_gemm2_kernel(
    const float* __restrict__ h, const float* __restrict__ wmsg,
    const float* __restrict__ wroot, const float* __restrict__ rb,
    const float* __restrict__ we, const float* __restrict__ mb,
    const float* __restrict__ ea_agg, const int* __restrict__ offsets,
    float* __restrict__ Hw, float* __restrict__ base) {
  __shared__ float4 hs[MT][H / 4];   // 16 KiB
  __shared__ float4 es[MT][ED / 4];  // 2 KiB
  __shared__ float degs[MT];
  int n0 = blockIdx.x * MT;
  int t = threadIdx.x;

  for (int i = t; i < MT * (H / 4); i += 128) {
    int n = i >> 5, c = i & 31;
    float4 v = make_float4(0.f, 0.f, 0.f, 0.f);
    if (n0 + n < NN) v = ((const float4*)(h + (size_t)(n0 + n) * H))[c];
    hs[n][c] = v;
  }
  {  // MT*(ED/4) == 128 exactly
    int n = t >> 2, c = t & 3;
    float4 v = make_float4(0.f, 0.f, 0.f, 0.f);
    if (n0 + n < NN) v = ((const float4*)(ea_agg + (size_t)(n0 + n) * ED))[c];
    es[n][c] = v;
  }
  if (t < MT) {
    int node = n0 + t;
    degs[t] = (node < NN) ? (float)(offsets[node + 1] - offsets[node]) : 0.f;
  }
  __syncthreads();

  int mat = t >> 6;             // wave-uniform
  int c0 = (t & 63) * 2;
  const float* W = mat ? wroot : wmsg;

  float acc0[MT], acc1[MT];
  float b0 = mat ? rb[c0] : 0.f;
  float b1 = mat ? rb[c0 + 1] : 0.f;
#pragma unroll
  for (int n = 0; n < MT; ++n) { acc0[n] = b0; acc1[n] = b1; }

  for (int j = 0; j < H; j += 4) {
    float2 wa = *(const float2*)&W[(j + 0) * H + c0];
    float2 wb = *(const float2*)&W[(j + 1) * H + c0];
    float2 wc = *(const float2*)&W[(j + 2) * H + c0];
    float2 wd = *(const float2*)&W[(j + 3) * H + c0];
#pragma unroll
    for (int n = 0; n < MT; ++n) {
      float4 hv = hs[n][j >> 2];
      acc0[n] = fmaf(hv.x, wa.x, acc0[n]); acc1[n] = fmaf(hv.x, wa.y, acc1[n]);
      acc0[n] = fmaf(hv.y, wb.x, acc0[n]); acc1[n] = fmaf(hv.y, wb.y, acc1[n]);
      acc0[n] = fmaf(hv.z, wc.x, acc0[n]); acc1[n] = fmaf(hv.z, wc.y, acc1[n]);
      acc0[n] = fmaf(hv.w, wd.x, acc0[n]); acc1[n] = fmaf(hv.w, wd.y, acc1[n]);
    }
  }

  if (mat) {  // wave-uniform branch: root wave adds edge path + identity
    float b0m = mb[c0], b1m = mb[c0 + 1];
    for (int j = 0; j < ED; j += 4) {
      float2 wa = *(const float2*)&we[(j + 0) * H + c0];
      float2 wb = *(const float2*)&we[(j + 1) * H + c0];
      float2 wc = *(const float2*)&we[(j + 2) * H + c0];
      float2 wd = *(const float2*)&we[(j + 3) * H + c0];
#pragma unroll
      for (int n = 0; n < MT; ++n) {
        float4 ev = es[n][j >> 2];
        acc0[n] = fmaf(ev.x, wa.x, acc0[n]); acc1[n] = fmaf(ev.x, wa.y, acc1[n]);
        acc0[n] = fmaf(ev.y, wb.x, acc0[n]); acc1[n] = fmaf(ev.y, wb.y, acc1[n]);
        acc0[n] = fmaf(ev.z, wc.x, acc0[n]); acc1[n] = fmaf(ev.z, wc.y, acc1[n]);
        acc0[n] = fmaf(ev.w, wd.x, acc0[n]); acc1[n] = fmaf(ev.w, wd.y, acc1[n]);
      }
    }
#pragma unroll
    for (int n = 0; n < MT; ++n) {
      float4 hv = hs[n][c0 >> 2];
      float i0 = (c0 & 2) ? hv.z : hv.x;
      float i1 = (c0 & 2) ? hv.w : hv.y;
      acc0[n] += i0 + degs[n] * b0m;
      acc1[n] += i1 + degs[n] * b1m;
    }
  }

  float* outp = mat ? base : Hw;
#pragma unroll
  for (int n = 0; n < MT; ++n) {
    if (n0 + n < NN)
      *(float2*)&outp[(size_t)(n0 + n) * H + c0] = make_float2(acc0[n], acc1[n]);
  }
}

// ---------------------------------------------------------------------------
// h[i] = act( base[i] + sum_{e->i} Hw[src[e]] )   — fused gather + update
// 32 threads per node, float4 per thread; 8 nodes per 256-thread block
// ---------------------------------------------------------------------------
__global__ __launch_bounds__(256) void gather_update_kernel(
    const int* __restrict__ offsets, const int* __restrict__ csr_src,
    const float* __restrict__ Hw, const float* __restrict__ base,
    float* __restrict__ h, int act) {
  int t = threadIdx.x;
  int node = blockIdx.x * 8 + (t >> 5);
  if (node >= NN) return;
  int k4 = (t & 31) * 4;
  int s = offsets[node], e = offsets[node + 1];
  float4 acc = *(const float4*)&base[(size_t)node * H + k4];
  for (int p = s; p < e; ++p) {
    int src = csr_src[p];
    float4 v = *(const float4*)&Hw[(size_t)src * H + k4];
    acc.x += v.x; acc.y += v.y; acc.z += v.z; acc.w += v.w;
  }
  if (act) {
    float* a = &acc.x;
#pragma unroll
    for (int j = 0; j < 4; ++j) {
      float v = a[j];
      float u = 0.7978845608028654f * (v + 0.044715f * v * v * v);
      a[j] = 0.5f * v * (1.f + tanhf(u));
    }
  }
  *(float4*)&h[(size_t)node * H + k4] = acc;
}

// ---------------------------------------------------------------------------
// out = h @ proj_w + proj_b     [NN, OD]
// ---------------------------------------------------------------------------
__global__ __launch_bounds__(256) void proj_kernel(
    const float* __restrict__ h, const float* __restrict__ pw,
    const float* __restrict__ pb, float* __restrict__ out) {
  int idx = blockIdx.x * 256 + threadIdx.x;
  if (idx >= NN * OD) return;
  int n = idx >> 2, o = idx & 3;
  float acc = pb[o];
  const float* hr = h + (size_t)n * H;
#pragma unroll
  for (int j = 0; j < H; ++j) acc = fmaf(hr[j], pw[j * OD + o], acc);
  out[idx] = acc;
}

extern "C" void kernel_launch(void* const* d_in, const int* in_sizes, int n_in,
                              void* d_out, int out_size, void* d_ws, size_t ws_size,
                              hipStream_t stream) {
  const float* x       = (const float*)d_in[0];
  const int*   ei      = (const int*)d_in[1];     // [2, NE] int32
  const float* ea      = (const float*)d_in[2];
  const float* lift_w  = (const float*)d_in[3];
  const float* lift_b  = (const float*)d_in[4];
  const float* root_w  = (const float*)d_in[5];   // [3,128,128]
  const float* root_b  = (const float*)d_in[6];   // [3,128]
  const float* msg_w   = (const float*)d_in[7];   // [3,144,128]
  const float* msg_b   = (const float*)d_in[8];   // [3,128]
  const float* proj_w  = (const float*)d_in[9];
  const float* proj_b  = (const float*)d_in[10];
  float* out = (float*)d_out;

  // workspace layout (~87 MB)
  float* h      = (float*)d_ws;                   // NN*H
  float* Hw     = h + (size_t)NN * H;             // NN*H
  float* base   = Hw + (size_t)NN * H;            // NN*H
  float* ea_agg = base + (size_t)NN * H;          // NN*ED
  int*   deg     = (int*)(ea_agg + (size_t)NN * ED);  // NN
  int*   cursor  = deg + NN;                      // NN
  int*   offsets = cursor + NN;                   // NN+1
  int*   tops    = offsets + NN + 1;              // 128
  int*   csr_src = tops + 128;                    // NE
  int*   csr_eid = csr_src + NE;                  // NE

  const int ntiles = (NN + SCAN_T - 1) / SCAN_T;  // 98

  // ---- CSR build (once per call) ----
  zero_kernel<<<(NN + 255) / 256, 256, 0, stream>>>(deg, cursor);
  degcount_kernel<<<(NE + 255) / 256, 256, 0, stream>>>(ei, deg);
  scan_part_kernel<<<ntiles, SCAN_T, 0, stream>>>(deg, offsets, tops);
  scan_tops_kernel<<<1, 64, 0, stream>>>(tops, ntiles, offsets);
  scan_add_kernel<<<(NN + 255) / 256, 256, 0, stream>>>(offsets, tops);
  csr_fill_kernel<<<(NE + 255) / 256, 256, 0, stream>>>(ei, offsets, cursor, csr_src, csr_eid);
  ea_agg_kernel<<<(NN + 15) / 16, 256, 0, stream>>>(offsets, csr_eid, ea, ea_agg);

  // ---- lift ----
  lift_kernel<<<(NN * H) / 256, 256, 0, stream>>>(x, lift_w, lift_b, h);

  // ---- blocks ----
  for (int b = 0; b < 3; ++b) {
    const float* wmsg = msg_w + (size_t)b * (H + ED) * H;   // rows 0..127
    const float* we   = wmsg + (size_t)H * H;               // rows 128..143
    const float* wrt  = root_w + (size_t)b * H * H;
    const float* rbb  = root_b + (size_t)b * H;
    const float* mbb  = msg_b + (size_t)b * H;

    node_gemm2_kernel<<<(NN + MT - 1) / MT, 128, 0, stream>>>(
        h, wmsg, wrt, rbb, we, mbb, ea_agg, offsets, Hw, base);
    gather_update_kernel<<<(NN + 7) / 8, 256, 0, stream>>>(
        offsets, csr_src, Hw, base, h, b < 2 ? 1 : 0);
  }

  proj_kernel<<<(NN * OD + 255) / 256, 256, 0, stream>>>(h, proj_w, proj_b, out);
}

// Round 3
// 398.731 us; speedup vs baseline: 4.0502x; 1.6215x over previous
//
#include <hip/hip_runtime.h>

// Problem constants (fixed by the reference)
#define NN 50000
#define NE 800000
#define ND 16
#define ED 16
#define H  128
#define OD 4
#define SCAN_T 512
#define KP 160      // padded K: 128 h + 16 ea_agg + deg + 1 + 14 zero
#define LDA 168     // LDS row stride (shorts) to break bank conflicts

typedef __bf16 bf16;
typedef __attribute__((ext_vector_type(8))) __bf16 bf16x8;
typedef __attribute__((ext_vector_type(4))) float f32x4;

static __device__ __forceinline__ float bf2f(unsigned short u) {
  return __builtin_bit_cast(float, (unsigned int)u << 16);
}

// ---------------------------------------------------------------------------
// CSR build (unchanged from R2 — known good)
// ---------------------------------------------------------------------------
__global__ __launch_bounds__(256) void zero_kernel(int* __restrict__ deg,
                                                   int* __restrict__ cursor) {
  int i = blockIdx.x * 256 + threadIdx.x;
  if (i < NN) { deg[i] = 0; cursor[i] = 0; }
}

__global__ __launch_bounds__(256) void degcount_kernel(
    const int* __restrict__ ei, int* __restrict__ deg) {
  int e = blockIdx.x * 256 + threadIdx.x;
  if (e < NE) atomicAdd(&deg[ei[NE + e]], 1);
}

__global__ __launch_bounds__(SCAN_T) void scan_part_kernel(
    const int* __restrict__ deg, int* __restrict__ offsets,
    int* __restrict__ tops) {
  __shared__ int s[SCAN_T];
  int t = threadIdx.x;
  int i = blockIdx.x * SCAN_T + t;
  int v = (i < NN) ? deg[i] : 0;
  s[t] = v;
  __syncthreads();
  for (int off = 1; off < SCAN_T; off <<= 1) {
    int a = (t >= off) ? s[t - off] : 0;
    __syncthreads();
    s[t] += a;
    __syncthreads();
  }
  if (i < NN) offsets[i] = s[t] - v;
  if (t == SCAN_T - 1) tops[blockIdx.x] = s[t];
}

__global__ void scan_tops_kernel(int* __restrict__ tops, int ntiles,
                                 int* __restrict__ offsets) {
  if (threadIdx.x == 0) {
    int run = 0;
    for (int b = 0; b < ntiles; ++b) { int v = tops[b]; tops[b] = run; run += v; }
    offsets[NN] = NE;
  }
}

__global__ __launch_bounds__(256) void scan_add_kernel(
    int* __restrict__ offsets, const int* __restrict__ tops) {
  int i = blockIdx.x * 256 + threadIdx.x;
  if (i < NN) offsets[i] += tops[i / SCAN_T];
}

__global__ __launch_bounds__(256) void csr_fill_kernel(
    const int* __restrict__ ei, const int* __restrict__ offsets,
    int* __restrict__ cursor, int* __restrict__ csr_src,
    int* __restrict__ csr_eid) {
  int e = blockIdx.x * 256 + threadIdx.x;
  if (e >= NE) return;
  int d = ei[NE + e];
  int pos = atomicAdd(&cursor[d], 1);
  int slot = offsets[d] + pos;
  csr_src[slot] = ei[e];
  csr_eid[slot] = e;
}

__global__ __launch_bounds__(256) void ea_agg_kernel(
    const int* __restrict__ offsets, const int* __restrict__ csr_eid,
    const float* __restrict__ ea, float* __restrict__ ea_agg) {
  int t = threadIdx.x;
  int node = blockIdx.x * 16 + (t >> 4);
  if (node >= NN) return;
  int k = t & 15;
  int s = offsets[node], e = offsets[node + 1];
  float acc = 0.f;
  for (int p = s; p < e; ++p)
    acc += ea[(size_t)csr_eid[p] * ED + k];
  ea_agg[(size_t)node * ED + k] = acc;
}

// ---------------------------------------------------------------------------
// A[:,128:160] static features: ea_agg(16) | deg | 1.0 | zeros(14)
// ---------------------------------------------------------------------------
__global__ __launch_bounds__(256) void static_fill_kernel(
    const float* __restrict__ ea_agg, const int* __restrict__ offsets,
    bf16* __restrict__ A) {
  int idx = blockIdx.x * 256 + threadIdx.x;   // NN*32 exact
  int node = idx >> 5, j = idx & 31;
  float v = 0.f;
  if (j < 16) v = ea_agg[(size_t)node * ED + j];
  else if (j == 16) v = (float)(offsets[node + 1] - offsets[node]);
  else if (j == 17) v = 1.0f;
  A[(size_t)node * KP + 128 + j] = (bf16)v;
}

// ---------------------------------------------------------------------------
// Pack W col-major: Wp[b][c][k] = W[b][k][c]
// ---------------------------------------------------------------------------
__global__ __launch_bounds__(256) void pack_w_kernel(
    const float* __restrict__ msg_w, const float* __restrict__ root_w,
    const float* __restrict__ root_b, const float* __restrict__ msg_b,
    bf16* __restrict__ Wp) {
  int idx = blockIdx.x * 256 + threadIdx.x;   // 3*256*160 exact
  int b = idx / (256 * KP);
  int r = idx % (256 * KP);
  int c = r / KP, k = r % KP;
  float v = 0.f;
  if (c < 128) {
    if (k < 128) v = msg_w[((size_t)b * 144 + k) * 128 + c];
  } else {
    int cc = c - 128;
    if (k < 128)       v = root_w[((size_t)b * 128 + k) * 128 + cc];
    else if (k < 144)  v = msg_w[((size_t)b * 144 + k) * 128 + cc];
    else if (k == 144) v = msg_b[(size_t)b * 128 + cc];
    else if (k == 145) v = root_b[(size_t)b * 128 + cc];
  }
  Wp[idx] = (bf16)v;
}

// ---------------------------------------------------------------------------
// lift: A[:,0:128] = bf16(x @ lift_w + lift_b)
// ---------------------------------------------------------------------------
__global__ __launch_bounds__(256) void lift_kernel(
    const float* __restrict__ x, const float* __restrict__ lw,
    const float* __restrict__ lb, bf16* __restrict__ A) {
  int idx = blockIdx.x * 256 + threadIdx.x;   // NN*128 exact
  int n = idx >> 7, k = idx & 127;
  float acc = lb[k];
  const float* xr = x + (size_t)n * ND;
#pragma unroll
  for (int j = 0; j < ND; ++j) acc = fmaf(xr[j], lw[j * H + k], acc);
  A[(size_t)n * KP + k] = (bf16)acc;
}

// ---------------------------------------------------------------------------
// MFMA GEMM: [NN x 160] @ [160 x 256] -> Hw (bf16) | base (f32, +identity)
// ---------------------------------------------------------------------------
__global__ __launch_bounds__(256, 2) void gemm_mfma_kernel(
    const bf16* __restrict__ A, const bf16* __restrict__ Wp,
    bf16* __restrict__ Hw, float* __restrict__ base) {
  __shared__ bf16 as[64 * LDA];
  int t = threadIdx.x;
  int lane = t & 63;
  int wv = t >> 6;
  int l15 = lane & 15, g = lane >> 4;
  int c0w = wv * 64;

  bf16x8 bq[5][4];
#pragma unroll
  for (int kk = 0; kk < 5; ++kk)
#pragma unroll
    for (int ni = 0; ni < 4; ++ni)
      bq[kk][ni] = *(const bf16x8*)(Wp + (size_t)(c0w + ni * 16 + l15) * KP + kk * 32 + g * 8);

  const int ntiles = (NN + 63) / 64;
  for (int tile = blockIdx.x; tile < ntiles; tile += gridDim.x) {
    int m0 = tile * 64;
    __syncthreads();
#pragma unroll
    for (int i = 0; i < 5; ++i) {
      int idx = i * 256 + t;
      int r = idx / 20, seg = idx % 20;
      int node = m0 + r;
      float4 v = make_float4(0.f, 0.f, 0.f, 0.f);
      if (node < NN) v = *(const float4*)(A + (size_t)node * KP + seg * 8);
      *(float4*)(as + r * LDA + seg * 8) = v;
    }
    __syncthreads();

    f32x4 acc[4][4];
#pragma unroll
    for (int mi = 0; mi < 4; ++mi)
#pragma unroll
      for (int ni = 0; ni < 4; ++ni)
        acc[mi][ni] = (f32x4){0.f, 0.f, 0.f, 0.f};

#pragma unroll
    for (int kk = 0; kk < 5; ++kk) {
      bf16x8 af[4];
#pragma unroll
      for (int mi = 0; mi < 4; ++mi)
        af[mi] = *(const bf16x8*)(as + (mi * 16 + l15) * LDA + kk * 32 + g * 8);
#pragma unroll
      for (int mi = 0; mi < 4; ++mi)
#pragma unroll
        for (int ni = 0; ni < 4; ++ni)
          acc[mi][ni] = __builtin_amdgcn_mfma_f32_16x16x32_bf16(
              af[mi], bq[kk][ni], acc[mi][ni], 0, 0, 0);
    }

#pragma unroll
    for (int mi = 0; mi < 4; ++mi) {
#pragma unroll
      for (int ni = 0; ni < 4; ++ni) {
#pragma unroll
        for (int i = 0; i < 4; ++i) {
          int rloc = mi * 16 + g * 4 + i;
          int row = m0 + rloc;
          int col = c0w + ni * 16 + l15;
          if (row < NN) {
            float v = acc[mi][ni][i];
            if (wv < 2) {
              Hw[(size_t)row * H + col] = (bf16)v;
            } else {
              int cc = col - 128;
              v += bf2f(__builtin_bit_cast(unsigned short, as[rloc * LDA + cc]));
              base[(size_t)row * H + cc] = v;
            }
          }
        }
      }
    }
  }
}

// ---------------------------------------------------------------------------
// h_next = act( base + sum_{e->i} Hw[src[e]] ) -> A[:,0:128] (bf16)
// ---------------------------------------------------------------------------
__global__ __launch_bounds__(256) void gather_update_kernel(
    const int* __restrict__ offsets, const int* __restrict__ csr_src,
    const bf16* __restrict__ Hw, const float* __restrict__ base,
    bf16* __restrict__ A, int act) {
  int t = threadIdx.x;
  int node = blockIdx.x * 8 + (t >> 5);
  if (node >= NN) return;
  int k4 = (t & 31) * 4;
  int s = offsets[node], e = offsets[node + 1];
  float4 acc = *(const float4*)&base[(size_t)node * H + k4];
  const unsigned short* Hu = (const unsigned short*)Hw;
  for (int p = s; p < e; ++p) {
    int src = csr_src[p];
    ushort4 v = *(const ushort4*)&Hu[(size_t)src * H + k4];
    acc.x += bf2f(v.x); acc.y += bf2f(v.y);
    acc.z += bf2f(v.z); acc.w += bf2f(v.w);
  }
  if (act) {
    float* a = &acc.x;
#pragma unroll
    for (int j = 0; j < 4; ++j) {
      float v = a[j];
      float u = 0.7978845608028654f * (v + 0.044715f * v * v * v);
      a[j] = 0.5f * v * (1.f + tanhf(u));
    }
  }
  ushort4 o;
  o.x = __builtin_bit_cast(unsigned short, (bf16)acc.x);
  o.y = __builtin_bit_cast(unsigned short, (bf16)acc.y);
  o.z = __builtin_bit_cast(unsigned short, (bf16)acc.z);
  o.w = __builtin_bit_cast(unsigned short, (bf16)acc.w);
  *(ushort4*)&((unsigned short*)A)[(size_t)node * KP + k4] = o;
}

// ---------------------------------------------------------------------------
// out = h @ proj_w + proj_b
// ---------------------------------------------------------------------------
__global__ __launch_bounds__(256) void proj_kernel(
    const bf16* __restrict__ A, const float* __restrict__ pw,
    const float* __restrict__ pb, float* __restrict__ out) {
  int idx = blockIdx.x * 256 + threadIdx.x;
  if (idx >= NN * OD) return;
  int n = idx >> 2, o = idx & 3;
  float acc = pb[o];
  const unsigned short* hr = (const unsigned short*)(A + (size_t)n * KP);
#pragma unroll
  for (int j = 0; j < H; ++j) acc = fmaf(bf2f(hr[j]), pw[j * OD + o], acc);
  out[idx] = acc;
}

extern "C" void kernel_launch(void* const* d_in, const int* in_sizes, int n_in,
                              void* d_out, int out_size, void* d_ws, size_t ws_size,
                              hipStream_t stream) {
  const float* x       = (const float*)d_in[0];
  const int*   ei      = (const int*)d_in[1];
  const float* ea      = (const float*)d_in[2];
  const float* lift_w  = (const float*)d_in[3];
  const float* lift_b  = (const float*)d_in[4];
  const float* root_w  = (const float*)d_in[5];
  const float* root_b  = (const float*)d_in[6];
  const float* msg_w   = (const float*)d_in[7];
  const float* msg_b   = (const float*)d_in[8];
  const float* proj_w  = (const float*)d_in[9];
  const float* proj_b  = (const float*)d_in[10];
  float* out = (float*)d_out;

  char* w = (char*)d_ws;
  bf16*  A      = (bf16*)w;              w += (size_t)NN * KP * 2;
  bf16*  Hw     = (bf16*)w;              w += (size_t)NN * H * 2;
  float* base   = (float*)w;             w += (size_t)NN * H * 4;
  float* ea_agg = (float*)w;             w += (size_t)NN * ED * 4;
  bf16*  Wp     = (bf16*)w;              w += (size_t)3 * 256 * KP * 2;
  int*   deg     = (int*)w;              w += (size_t)NN * 4;
  int*   cursor  = (int*)w;              w += (size_t)NN * 4;
  int*   offsets = (int*)w;              w += (size_t)(NN + 16) * 4;
  int*   tops    = (int*)w;              w += 128 * 4;
  int*   csr_src = (int*)w;              w += (size_t)NE * 4;
  int*   csr_eid = (int*)w;

  const int ntiles = (NN + SCAN_T - 1) / SCAN_T;

  zero_kernel<<<(NN + 255) / 256, 256, 0, stream>>>(deg, cursor);
  degcount_kernel<<<(NE + 255) / 256, 256, 0, stream>>>(ei, deg);
  scan_part_kernel<<<ntiles, SCAN_T, 0, stream>>>(deg, offsets, tops);
  scan_tops_kernel<<<1, 64, 0, stream>>>(tops, ntiles, offsets);
  scan_add_kernel<<<(NN + 255) / 256, 256, 0, stream>>>(offsets, tops);
  csr_fill_kernel<<<(NE + 255) / 256, 256, 0, stream>>>(ei, offsets, cursor, csr_src, csr_eid);
  ea_agg_kernel<<<(NN + 15) / 16, 256, 0, stream>>>(offsets, csr_eid, ea, ea_agg);

  static_fill_kernel<<<(NN * 32) / 256, 256, 0, stream>>>(ea_agg, offsets, A);
  pack_w_kernel<<<(3 * 256 * KP) / 256, 256, 0, stream>>>(msg_w, root_w, root_b, msg_b, Wp);
  lift_kernel<<<(NN * H) / 256, 256, 0, stream>>>(x, lift_w, lift_b, A);

  for (int b = 0; b < 3; ++b) {
    gemm_mfma_kernel<<<512, 256, 0, stream>>>(A, Wp + (size_t)b * 256 * KP, Hw, base);
    gather_update_kernel<<<NN / 8, 256, 0, stream>>>(
        offsets, csr_src, Hw, base, A, b < 2 ? 1 : 0);
  }

  proj_kernel<<<(NN * OD + 255) / 256, 256, 0, stream>>>(A, proj_w, proj_b, out);
}

// Round 4
// 352.571 us; speedup vs baseline: 4.5805x; 1.1309x over previous
//
#include <hip/hip_runtime.h>

// Problem constants (fixed by the reference)
#define NN 50000
#define NE 800000
#define ND 16
#define ED 16
#define H  128
#define OD 4
#define SCAN_T 512
#define KP 160      // padded K: 128 h + 16 ea_agg + deg + 1 + 14 zero
#define LDA 168     // LDS row stride (shorts) to break bank conflicts

typedef __bf16 bf16;
typedef __attribute__((ext_vector_type(8))) __bf16 bf16x8;
typedef __attribute__((ext_vector_type(4))) float f32x4;

static __device__ __forceinline__ float bf2f(unsigned short u) {
  return __builtin_bit_cast(float, (unsigned int)u << 16);
}
static __device__ __forceinline__ unsigned short f2bfu(float f) {
  return __builtin_bit_cast(unsigned short, (bf16)f);
}

// ---------------------------------------------------------------------------
// CSR build
// ---------------------------------------------------------------------------
__global__ __launch_bounds__(256) void zero_kernel(int* __restrict__ deg,
                                                   int* __restrict__ cursor) {
  int i = blockIdx.x * 256 + threadIdx.x;
  if (i < NN) { deg[i] = 0; cursor[i] = 0; }
}

__global__ __launch_bounds__(256) void degcount_kernel(
    const int* __restrict__ ei, int* __restrict__ deg) {
  int e = blockIdx.x * 256 + threadIdx.x;
  if (e < NE) atomicAdd(&deg[ei[NE + e]], 1);
}

__global__ __launch_bounds__(SCAN_T) void scan_part_kernel(
    const int* __restrict__ deg, int* __restrict__ offsets,
    int* __restrict__ tops) {
  __shared__ int s[SCAN_T];
  int t = threadIdx.x;
  int i = blockIdx.x * SCAN_T + t;
  int v = (i < NN) ? deg[i] : 0;
  s[t] = v;
  __syncthreads();
  for (int off = 1; off < SCAN_T; off <<= 1) {
    int a = (t >= off) ? s[t - off] : 0;
    __syncthreads();
    s[t] += a;
    __syncthreads();
  }
  if (i < NN) offsets[i] = s[t] - v;
  if (t == SCAN_T - 1) tops[blockIdx.x] = s[t];
}

__global__ void scan_tops_kernel(int* __restrict__ tops, int ntiles,
                                 int* __restrict__ offsets) {
  if (threadIdx.x == 0) {
    int run = 0;
    for (int b = 0; b < ntiles; ++b) { int v = tops[b]; tops[b] = run; run += v; }
    offsets[NN] = NE;
  }
}

__global__ __launch_bounds__(256) void scan_add_kernel(
    int* __restrict__ offsets, const int* __restrict__ tops) {
  int i = blockIdx.x * 256 + threadIdx.x;
  if (i < NN) offsets[i] += tops[i / SCAN_T];
}

// one int2 store per edge: (src, eid) — single cacheline touch
__global__ __launch_bounds__(256) void csr_fill_kernel(
    const int* __restrict__ ei, const int* __restrict__ offsets,
    int* __restrict__ cursor, int2* __restrict__ csr) {
  int e = blockIdx.x * 256 + threadIdx.x;
  if (e >= NE) return;
  int d = ei[NE + e];
  int pos = atomicAdd(&cursor[d], 1);
  csr[offsets[d] + pos] = make_int2(ei[e], e);
}

// ---------------------------------------------------------------------------
// A[:,128:160] = [ sum_{e->i} ea[e] (16) | deg | 1.0 | zeros(14) ]  (bf16)
// 16 lanes per node; ea reads coalesced (lane k -> ea[eid*16+k])
// ---------------------------------------------------------------------------
__global__ __launch_bounds__(256) void edge_static_kernel(
    const int* __restrict__ offsets, const int2* __restrict__ csr,
    const float* __restrict__ ea, bf16* __restrict__ A) {
  int t = threadIdx.x;
  int node = blockIdx.x * 16 + (t >> 4);   // NN/16 exact
  int k = t & 15;
  int s = offsets[node], e = offsets[node + 1];
  const int* ci = (const int*)csr;
  float acc = 0.f;
  for (int p = s; p < e; ++p)
    acc += ea[(size_t)ci[2 * p + 1] * ED + k];
  unsigned short* Au = (unsigned short*)A;
  Au[(size_t)node * KP + 128 + k] = f2bfu(acc);
  float v2 = (k == 0) ? (float)(e - s) : (k == 1 ? 1.0f : 0.0f);
  Au[(size_t)node * KP + 144 + k] = f2bfu(v2);
}

// ---------------------------------------------------------------------------
// Pack W col-major: Wp[b][c][k] = W[b][k][c]
// ---------------------------------------------------------------------------
__global__ __launch_bounds__(256) void pack_w_kernel(
    const float* __restrict__ msg_w, const float* __restrict__ root_w,
    const float* __restrict__ root_b, const float* __restrict__ msg_b,
    bf16* __restrict__ Wp) {
  int idx = blockIdx.x * 256 + threadIdx.x;   // 3*256*160 exact
  int b = idx / (256 * KP);
  int r = idx % (256 * KP);
  int c = r / KP, k = r % KP;
  float v = 0.f;
  if (c < 128) {
    if (k < 128) v = msg_w[((size_t)b * 144 + k) * 128 + c];
  } else {
    int cc = c - 128;
    if (k < 128)       v = root_w[((size_t)b * 128 + k) * 128 + cc];
    else if (k < 144)  v = msg_w[((size_t)b * 144 + k) * 128 + cc];
    else if (k == 144) v = msg_b[(size_t)b * 128 + cc];
    else if (k == 145) v = root_b[(size_t)b * 128 + cc];
  }
  Wp[idx] = (bf16)v;
}

// ---------------------------------------------------------------------------
// lift: A[:,0:128] = bf16(x @ lift_w + lift_b)
// ---------------------------------------------------------------------------
__global__ __launch_bounds__(256) void lift_kernel(
    const float* __restrict__ x, const float* __restrict__ lw,
    const float* __restrict__ lb, bf16* __restrict__ A) {
  int idx = blockIdx.x * 256 + threadIdx.x;   // NN*128 exact
  int n = idx >> 7, k = idx & 127;
  float acc = lb[k];
  const float* xr = x + (size_t)n * ND;
#pragma unroll
  for (int j = 0; j < ND; ++j) acc = fmaf(xr[j], lw[j * H + k], acc);
  A[(size_t)n * KP + k] = (bf16)acc;
}

// ---------------------------------------------------------------------------
// MFMA GEMM: [NN x 160] @ [160 x 256] -> Hw (bf16) | base (f32, +identity)
// ---------------------------------------------------------------------------
__global__ __launch_bounds__(256, 2) void gemm_mfma_kernel(
    const bf16* __restrict__ A, const bf16* __restrict__ Wp,
    bf16* __restrict__ Hw, float* __restrict__ base) {
  __shared__ bf16 as[64 * LDA];
  int t = threadIdx.x;
  int lane = t & 63;
  int wv = t >> 6;
  int l15 = lane & 15, g = lane >> 4;
  int c0w = wv * 64;

  bf16x8 bq[5][4];
#pragma unroll
  for (int kk = 0; kk < 5; ++kk)
#pragma unroll
    for (int ni = 0; ni < 4; ++ni)
      bq[kk][ni] = *(const bf16x8*)(Wp + (size_t)(c0w + ni * 16 + l15) * KP + kk * 32 + g * 8);

  const int ntiles = (NN + 63) / 64;
  for (int tile = blockIdx.x; tile < ntiles; tile += gridDim.x) {
    int m0 = tile * 64;
    __syncthreads();
#pragma unroll
    for (int i = 0; i < 5; ++i) {
      int idx = i * 256 + t;
      int r = idx / 20, seg = idx % 20;
      int node = m0 + r;
      float4 v = make_float4(0.f, 0.f, 0.f, 0.f);
      if (node < NN) v = *(const float4*)(A + (size_t)node * KP + seg * 8);
      *(float4*)(as + r * LDA + seg * 8) = v;
    }
    __syncthreads();

    f32x4 acc[4][4];
#pragma unroll
    for (int mi = 0; mi < 4; ++mi)
#pragma unroll
      for (int ni = 0; ni < 4; ++ni)
        acc[mi][ni] = (f32x4){0.f, 0.f, 0.f, 0.f};

#pragma unroll
    for (int kk = 0; kk < 5; ++kk) {
      bf16x8 af[4];
#pragma unroll
      for (int mi = 0; mi < 4; ++mi)
        af[mi] = *(const bf16x8*)(as + (mi * 16 + l15) * LDA + kk * 32 + g * 8);
#pragma unroll
      for (int mi = 0; mi < 4; ++mi)
#pragma unroll
        for (int ni = 0; ni < 4; ++ni)
          acc[mi][ni] = __builtin_amdgcn_mfma_f32_16x16x32_bf16(
              af[mi], bq[kk][ni], acc[mi][ni], 0, 0, 0);
    }

#pragma unroll
    for (int mi = 0; mi < 4; ++mi) {
#pragma unroll
      for (int ni = 0; ni < 4; ++ni) {
#pragma unroll
        for (int i = 0; i < 4; ++i) {
          int rloc = mi * 16 + g * 4 + i;
          int row = m0 + rloc;
          int col = c0w + ni * 16 + l15;
          if (row < NN) {
            float v = acc[mi][ni][i];
            if (wv < 2) {
              Hw[(size_t)row * H + col] = (bf16)v;
            } else {
              int cc = col - 128;
              v += bf2f(__builtin_bit_cast(unsigned short, as[rloc * LDA + cc]));
              base[(size_t)row * H + cc] = v;
            }
          }
        }
      }
    }
  }
}

// ---------------------------------------------------------------------------
// h_next = act( base + sum_{e->i} Hw[src[e]] ) -> A[:,0:128] (bf16)
// 16 lanes x 16B per node; 16 nodes per 256-thread block
// ---------------------------------------------------------------------------
__global__ __launch_bounds__(256) void gather_update_kernel(
    const int* __restrict__ offsets, const int2* __restrict__ csr,
    const bf16* __restrict__ Hw, const float* __restrict__ base,
    bf16* __restrict__ A, int act) {
  int t = threadIdx.x;
  int node = blockIdx.x * 16 + (t >> 4);   // NN/16 exact
  int li = t & 15;
  int k8 = li * 8;
  int s = offsets[node], e = offsets[node + 1];
  const int* ci = (const int*)csr;
  const unsigned short* Hu = (const unsigned short*)Hw;

  float acc[8];
  {
    float4 b0 = *(const float4*)&base[(size_t)node * H + k8];
    float4 b1 = *(const float4*)&base[(size_t)node * H + k8 + 4];
    acc[0] = b0.x; acc[1] = b0.y; acc[2] = b0.z; acc[3] = b0.w;
    acc[4] = b1.x; acc[5] = b1.y; acc[6] = b1.z; acc[7] = b1.w;
  }

  for (int p = s; p < e; ++p) {
    int src = ci[2 * p];
    uint4 v = *(const uint4*)&Hu[(size_t)src * H + k8];
    acc[0] += bf2f((unsigned short)(v.x & 0xffff));
    acc[1] += bf2f((unsigned short)(v.x >> 16));
    acc[2] += bf2f((unsigned short)(v.y & 0xffff));
    acc[3] += bf2f((unsigned short)(v.y >> 16));
    acc[4] += bf2f((unsigned short)(v.z & 0xffff));
    acc[5] += bf2f((unsigned short)(v.z >> 16));
    acc[6] += bf2f((unsigned short)(v.w & 0xffff));
    acc[7] += bf2f((unsigned short)(v.w >> 16));
  }

  if (act) {
#pragma unroll
    for (int j = 0; j < 8; ++j) {
      float v = acc[j];
      float u = 0.7978845608028654f * (v + 0.044715f * v * v * v);
      acc[j] = 0.5f * v * (1.f + tanhf(u));
    }
  }

  uint4 o;
  o.x = (unsigned int)f2bfu(acc[0]) | ((unsigned int)f2bfu(acc[1]) << 16);
  o.y = (unsigned int)f2bfu(acc[2]) | ((unsigned int)f2bfu(acc[3]) << 16);
  o.z = (unsigned int)f2bfu(acc[4]) | ((unsigned int)f2bfu(acc[5]) << 16);
  o.w = (unsigned int)f2bfu(acc[6]) | ((unsigned int)f2bfu(acc[7]) << 16);
  *(uint4*)&((unsigned short*)A)[(size_t)node * KP + k8] = o;
}

// ---------------------------------------------------------------------------
// out = h @ proj_w + proj_b
// ---------------------------------------------------------------------------
__global__ __launch_bounds__(256) void proj_kernel(
    const bf16* __restrict__ A, const float* __restrict__ pw,
    const float* __restrict__ pb, float* __restrict__ out) {
  int idx = blockIdx.x * 256 + threadIdx.x;
  if (idx >= NN * OD) return;
  int n = idx >> 2, o = idx & 3;
  float acc = pb[o];
  const unsigned short* hr = (const unsigned short*)(A + (size_t)n * KP);
#pragma unroll
  for (int j = 0; j < H; ++j) acc = fmaf(bf2f(hr[j]), pw[j * OD + o], acc);
  out[idx] = acc;
}

extern "C" void kernel_launch(void* const* d_in, const int* in_sizes, int n_in,
                              void* d_out, int out_size, void* d_ws, size_t ws_size,
                              hipStream_t stream) {
  const float* x       = (const float*)d_in[0];
  const int*   ei      = (const int*)d_in[1];
  const float* ea      = (const float*)d_in[2];
  const float* lift_w  = (const float*)d_in[3];
  const float* lift_b  = (const float*)d_in[4];
  const float* root_w  = (const float*)d_in[5];
  const float* root_b  = (const float*)d_in[6];
  const float* msg_w   = (const float*)d_in[7];
  const float* msg_b   = (const float*)d_in[8];
  const float* proj_w  = (const float*)d_in[9];
  const float* proj_b  = (const float*)d_in[10];
  float* out = (float*)d_out;

  char* w = (char*)d_ws;
  bf16*  A      = (bf16*)w;              w += (size_t)NN * KP * 2;       // 16.0 MB
  bf16*  Hw     = (bf16*)w;              w += (size_t)NN * H * 2;        // 12.8 MB
  float* base   = (float*)w;             w += (size_t)NN * H * 4;        // 25.6 MB
  bf16*  Wp     = (bf16*)w;              w += (size_t)3 * 256 * KP * 2;  // 0.25 MB
  int2*  csr    = (int2*)w;              w += (size_t)NE * 8;            // 6.4 MB
  int*   deg     = (int*)w;              w += (size_t)NN * 4;
  int*   cursor  = (int*)w;              w += (size_t)NN * 4;
  int*   offsets = (int*)w;              w += (size_t)(NN + 16) * 4;
  int*   tops    = (int*)w;

  const int ntiles = (NN + SCAN_T - 1) / SCAN_T;  // 98

  zero_kernel<<<(NN + 255) / 256, 256, 0, stream>>>(deg, cursor);
  degcount_kernel<<<(NE + 255) / 256, 256, 0, stream>>>(ei, deg);
  scan_part_kernel<<<ntiles, SCAN_T, 0, stream>>>(deg, offsets, tops);
  scan_tops_kernel<<<1, 64, 0, stream>>>(tops, ntiles, offsets);
  scan_add_kernel<<<(NN + 255) / 256, 256, 0, stream>>>(offsets, tops);
  csr_fill_kernel<<<(NE + 255) / 256, 256, 0, stream>>>(ei, offsets, cursor, csr);

  edge_static_kernel<<<NN / 16, 256, 0, stream>>>(offsets, csr, ea, A);
  pack_w_kernel<<<(3 * 256 * KP) / 256, 256, 0, stream>>>(msg_w, root_w, root_b, msg_b, Wp);
  lift_kernel<<<(NN * H) / 256, 256, 0, stream>>>(x, lift_w, lift_b, A);

  for (int b = 0; b < 3; ++b) {
    gemm_mfma_kernel<<<512, 256, 0, stream>>>(A, Wp + (size_t)b * 256 * KP, Hw, base);
    gather_update_kernel<<<NN / 16, 256, 0, stream>>>(
        offsets, csr, Hw, base, A, b < 2 ? 1 : 0);
  }

  proj_kernel<<<(NN * OD + 255) / 256, 256, 0, stream>>>(A, proj_w, proj_b, out);
}